// Round 12
// baseline (8402.670 us; speedup 1.0000x reference)
//
#include <hip/hip_runtime.h>
#include <hip/hip_bf16.h>
#include <math.h>

#define T_STEPS 512
#define BATCH   64
#define HID     1024
#define G3      3072
#define BH      (BATCH * HID)

typedef __attribute__((ext_vector_type(8))) short          bf16x8;
typedef __attribute__((ext_vector_type(8))) unsigned short u16x8;
typedef __attribute__((ext_vector_type(4))) float          f32x4;
typedef unsigned long long u64;

__device__ inline unsigned short f2bf(float f) {
    __hip_bfloat16 h = __float2bfloat16(f);
    return *reinterpret_cast<unsigned short*>(&h);
}

// agent-scope (cross-XCD coherent) 16B load of bf16x8, bypassing stale L1/L2
__device__ inline bf16x8 load_h8(const unsigned short* p) {
    u64 lo = __hip_atomic_load((const u64*)p,       __ATOMIC_RELAXED, __HIP_MEMORY_SCOPE_AGENT);
    u64 hi = __hip_atomic_load((const u64*)(p + 4), __ATOMIC_RELAXED, __HIP_MEMORY_SCOPE_AGENT);
    union { u64 q[2]; bf16x8 v; } u;
    u.q[0] = lo; u.q[1] = hi;
    return u.v;
}

__device__ inline float fast_sigmoid(float x) {
    return __builtin_amdgcn_rcpf(1.f + __expf(-x));
}
__device__ inline float fast_tanh(float x) {
    float e = __expf(-2.f * fabsf(x));
    float t = (1.f - e) * __builtin_amdgcn_rcpf(1.f + e);
    return copysignf(t, x);
}

// ---------------------------------------------------------------------------
__global__ void cvt_f32_bf16(const float* __restrict__ src,
                             unsigned short* __restrict__ dst, int n)
{
    int i = (blockIdx.x * blockDim.x + threadIdx.x) * 4;
    if (i + 3 < n) {
        float4 v = *(const float4*)(src + i);
        ushort4 o;
        o.x = f2bf(v.x); o.y = f2bf(v.y); o.z = f2bf(v.z); o.w = f2bf(v.w);
        *(ushort4*)(dst + i) = o;
    }
}

// ---------------------------------------------------------------------------
// gx GEMM: C[M][3072] = A[M][1024](f32, cvt on the fly) @ Wbf[3072][1024]^T + b
// ---------------------------------------------------------------------------
__global__ __launch_bounds__(256) void gemm_gx_bf16(
    const float* __restrict__ A, const unsigned short* __restrict__ Wbf,
    const float* __restrict__ bias, float* __restrict__ C, int M)
{
    __shared__ unsigned short As[128][72];
    __shared__ unsigned short Bs[128][72];
    const int tid = threadIdx.x;
    const int l  = tid & 63;
    const int w  = tid >> 6;
    const int wm = w >> 1, wn = w & 1;
    const int m0 = blockIdx.y * 128, n0 = blockIdx.x * 128;
    const int lr = l & 15, lk = (l >> 4) * 8;

    f32x4 acc[4][4] = {};

    const int arow = tid >> 4, acol = (tid & 15) * 4;
    const int brow = tid >> 3, bcol = (tid & 7) * 8;

    for (int k0 = 0; k0 < 1024; k0 += 64) {
        float4 av[8];
        #pragma unroll
        for (int r = 0; r < 8; ++r)
            av[r] = *(const float4*)(A + (size_t)(m0 + r * 16 + arow) * 1024 + k0 + acol);
        u16x8 bv[4];
        #pragma unroll
        for (int r = 0; r < 4; ++r)
            bv[r] = *(const u16x8*)(Wbf + (size_t)(n0 + r * 32 + brow) * 1024 + k0 + bcol);

        __syncthreads();
        #pragma unroll
        for (int r = 0; r < 8; ++r) {
            ushort4 o;
            o.x = f2bf(av[r].x); o.y = f2bf(av[r].y);
            o.z = f2bf(av[r].z); o.w = f2bf(av[r].w);
            *(ushort4*)&As[r * 16 + arow][acol] = o;
        }
        #pragma unroll
        for (int r = 0; r < 4; ++r)
            *(u16x8*)&Bs[r * 32 + brow][bcol] = bv[r];
        __syncthreads();

        #pragma unroll
        for (int kk = 0; kk < 2; ++kk) {
            bf16x8 af[4], bfr[4];
            #pragma unroll
            for (int i = 0; i < 4; ++i)
                af[i] = *(const bf16x8*)&As[wm * 64 + i * 16 + lr][kk * 32 + lk];
            #pragma unroll
            for (int j = 0; j < 4; ++j)
                bfr[j] = *(const bf16x8*)&Bs[wn * 64 + j * 16 + lr][kk * 32 + lk];
            #pragma unroll
            for (int i = 0; i < 4; ++i)
                #pragma unroll
                for (int j = 0; j < 4; ++j)
                    acc[i][j] = __builtin_amdgcn_mfma_f32_16x16x32_bf16(
                        af[i], bfr[j], acc[i][j], 0, 0, 0);
        }
    }

    #pragma unroll
    for (int j = 0; j < 4; ++j) {
        const int col = n0 + wn * 64 + j * 16 + lr;
        const float bv = bias[col];
        #pragma unroll
        for (int i = 0; i < 4; ++i) {
            const int rb = m0 + wm * 64 + i * 16 + (l >> 4) * 4;
            #pragma unroll
            for (int r = 0; r < 4; ++r)
                C[(size_t)(rb + r) * G3 + col] = acc[i][j][r] + bv;
        }
    }
}

// ---------------------------------------------------------------------------
// Persistent recurrence — round-5 topology, per-wave flag protocol.
// 256 blocks x 256 thr, block = (jt = bid&63, bg = bid>>6); 4 waves split K.
// Producer: each wave drains ITS OWN vmcnt after its h stores and publishes
// flags[bg*256 + jt*4 + ks] (no block barrier on the arrive path).
// Consumer: wave ks needs h cols [ks*256, ks*256+256) = blocks jt in
// [ks*16, ks*16+16) x 4 waves = 64 flags = one word per lane (one coalesced
// 256B poll load), then proceeds straight into its h loads + MFMAs with no
// block barrier. Overwrite safety: any wave's h-store of step t sits after
// barriers B1/B2, by which point all 4 waves' polls have collectively
// confirmed all 64 producer blocks finished step t-1 (done reading h(t-2)),
// so the depth-2 ping-pong invariant from the verified round-5 kernel holds.
// ---------------------------------------------------------------------------
__global__ __launch_bounds__(256, 1) void gru_persist(
    const float* __restrict__ gx,            // [tc][64][3072] chunk-local
    unsigned short* __restrict__ hbf,        // 2 x [64][1024], parity = t&1
    const float* __restrict__ hprev0,        // [64][1024] f32 h before step t0
    const unsigned short* __restrict__ whh,  // [3072][1024] bf16
    const float* __restrict__ bhh,           // [3072]
    float* __restrict__ y_all,               // [512][64][1024]
    float* __restrict__ hn_dst,              // [64][1024] (this layer's hn)
    unsigned int* __restrict__ flags,        // [4][64][4] = bg*256 + jt*4 + ks
    int step_base, int t0, int tc)
{
    __shared__ float red[4][64][13];

    const int tid = threadIdx.x;
    const int bid = blockIdx.x;
    const int jt = bid & 63;
    const int bg = bid >> 6;
    const int l   = tid & 63;
    const int ks  = tid >> 6;          // wave = k-slice (256 k)
    const int lr  = l & 15;
    const int lgrp = l >> 4;

    const unsigned short* hpb = hbf + (size_t)(bg * 16 + lr) * HID + ks * 256 + lgrp * 8;
    const unsigned short* wr  = whh + (size_t)(jt * 16 + lr) * HID + ks * 256 + lgrp * 8;
    const unsigned short* wz  = wr + (size_t)HID * HID;
    const unsigned short* wn  = wz + (size_t)HID * HID;

    // hoist this wave's W_hh slice into registers (loop-invariant)
    bf16x8 wvr[8], wvz[8], wvn[8];
    #pragma unroll
    for (int kc = 0; kc < 8; ++kc) {
        wvr[kc] = *(const bf16x8*)(wr + kc * 32);
        wvz[kc] = *(const bf16x8*)(wz + kc * 32);
        wvn[kc] = *(const bf16x8*)(wn + kc * 32);
    }

    // finalize coords: thread (fl, q) -> (col j, batch b)
    const int q  = tid >> 6;
    const int fl = tid & 63;
    const int j  = jt * 16 + (fl & 15);
    const int b  = bg * 16 + 4 * (fl >> 4) + q;
    const float brc = bhh[j], bzc = bhh[HID + j], bnc = bhh[2 * HID + j];
    float hreg = hprev0[(size_t)b * HID + j];

    unsigned int* myflag = flags + bg * 256 + jt * 4 + ks;       // producer word
    const unsigned int* pollf = flags + bg * 256 + ks * 64 + l;  // = (ks*16+(l>>2))*4+(l&3)

    for (int ts = 0; ts < tc; ++ts) {
        const int t = t0 + ts;
        const size_t coff = (size_t)(t & 1) * BH;
        const size_t noff = (size_t)((t + 1) & 1) * BH;
        const unsigned int need  = (unsigned int)(step_base + ts);
        const unsigned int stamp = need + 1;

        // gx loads issued early — independent of h, consumed at finalize
        const float* gx_t = gx + (size_t)ts * BATCH * G3;
        const float gxr = gx_t[(size_t)b * G3 + j];
        const float gxz = gx_t[(size_t)b * G3 + HID + j];
        const float gxn = gx_t[(size_t)b * G3 + 2 * HID + j];

        // per-wave poll: this wave's 16 producer blocks x 4 waves, 1 word/lane
        for (;;) {
            unsigned int f = __hip_atomic_load(pollf, __ATOMIC_RELAXED,
                                               __HIP_MEMORY_SCOPE_AGENT);
            if (__ballot(f < need) == 0ull) break;
            __builtin_amdgcn_s_sleep(1);
        }
        __builtin_amdgcn_sched_barrier(0);   // keep h loads below the poll

        // MFMA over this wave's 256-k slice
        f32x4 ar = {0.f, 0.f, 0.f, 0.f};
        f32x4 az = {0.f, 0.f, 0.f, 0.f};
        f32x4 an = {0.f, 0.f, 0.f, 0.f};
        #pragma unroll
        for (int kc = 0; kc < 8; ++kc) {
            bf16x8 a = load_h8(hpb + coff + kc * 32);
            ar = __builtin_amdgcn_mfma_f32_16x16x32_bf16(a, wvr[kc], ar, 0, 0, 0);
            az = __builtin_amdgcn_mfma_f32_16x16x32_bf16(a, wvz[kc], az, 0, 0, 0);
            an = __builtin_amdgcn_mfma_f32_16x16x32_bf16(a, wvn[kc], an, 0, 0, 0);
        }
        #pragma unroll
        for (int i = 0; i < 4; ++i) {
            red[ks][l][i]     = ar[i];
            red[ks][l][4 + i] = az[i];
            red[ks][l][8 + i] = an[i];
        }
        __syncthreads();   // B1: red visible to all waves

        float sr = 0.f, sz = 0.f, sn = 0.f;
        #pragma unroll
        for (int s = 0; s < 4; ++s) {
            sr += red[s][fl][q];
            sz += red[s][fl][4 + q];
            sn += red[s][fl][8 + q];
        }
        __syncthreads();   // B2: red consumed; next iter's red writes are safe

        const float rg = fast_sigmoid(gxr + sr + brc);
        const float zg = fast_sigmoid(gxz + sz + bzc);
        const float ng = fast_tanh(gxn + rg * (sn + bnc));
        hreg = ng + zg * (hreg - ng);

        // packed 4B agent-scope h store (lane pair shares one dword)
        unsigned int myu = (unsigned int)f2bf(hreg);
        unsigned int pu  = __shfl_xor(myu, 1);
        if (!(fl & 1))
            __hip_atomic_store((unsigned int*)(hbf + noff + (size_t)b * HID + j),
                               myu | (pu << 16),
                               __ATOMIC_RELAXED, __HIP_MEMORY_SCOPE_AGENT);

        // per-wave release: drain THIS wave's h stores, then publish its flag
        asm volatile("s_waitcnt vmcnt(0)" ::: "memory");
        if (l == 0)
            __hip_atomic_store(myflag, stamp,
                               __ATOMIC_RELAXED, __HIP_MEMORY_SCOPE_AGENT);

        // off the arrive path: y store + hn store (complete under next poll)
        y_all[(size_t)t * BH + (size_t)b * HID + j] = hreg;
        if (t == T_STEPS - 1)
            hn_dst[(size_t)b * HID + j] = hreg;
    }
}

// ---------------------------------------------------------------------------
extern "C" void kernel_launch(void* const* d_in, const int* in_sizes, int n_in,
                              void* d_out, int out_size, void* d_ws, size_t ws_size,
                              hipStream_t stream)
{
    const float* x    = (const float*)d_in[0];
    const float* h0   = (const float*)d_in[1];
    const float* wih[2] = {(const float*)d_in[2], (const float*)d_in[6]};
    const float* whh[2] = {(const float*)d_in[3], (const float*)d_in[7]};
    const float* bih[2] = {(const float*)d_in[4], (const float*)d_in[8]};
    const float* bhh[2] = {(const float*)d_in[5], (const float*)d_in[9]};

    float* out = (float*)d_out;
    float* y   = out;                                  // [512][64][1024]
    float* hn  = out + (size_t)T_STEPS * BH;           // [2][64][1024]

    const size_t WSZ = (size_t)G3 * HID;               // 3145728 elems
    unsigned short* wsu = (unsigned short*)d_ws;
    unsigned short* whh_bf[2] = {wsu, wsu + WSZ};
    unsigned short* wih_bf[2] = {wsu + 2 * WSZ, wsu + 3 * WSZ};
    unsigned short* hbf = wsu + 4 * WSZ;               // 2 x BH bf16 ping-pong
    unsigned int* flags = (unsigned int*)(wsu + 4 * WSZ + 2 * (size_t)BH);
    const size_t FLAG_N = 4 * 64 * 4;                  // [bg][jt][wave]
    float* gx = (float*)((char*)flags + FLAG_N * sizeof(unsigned int));
    const size_t fixed_bytes = (4 * WSZ + 2 * (size_t)BH) * 2 + FLAG_N * 4;
    const size_t gx_bytes = ws_size > fixed_bytes ? ws_size - fixed_bytes : 0;

    int TC = 512;
    while (TC > 2 && (size_t)TC * BATCH * G3 * 4 > gx_bytes) TC >>= 1;

    hipMemsetAsync(flags, 0, FLAG_N * sizeof(unsigned int), stream);

    for (int layer = 0; layer < 2; ++layer) {
        cvt_f32_bf16<<<(int)(WSZ / 1024), 256, 0, stream>>>(whh[layer], whh_bf[layer], (int)WSZ);
        cvt_f32_bf16<<<(int)(WSZ / 1024), 256, 0, stream>>>(wih[layer], wih_bf[layer], (int)WSZ);
    }

    for (int layer = 0; layer < 2; ++layer) {
        const float* A_all = (layer == 0) ? x : y;
        const float* hinit = h0 + (size_t)layer * BH;

        cvt_f32_bf16<<<BH / 1024, 256, 0, stream>>>(hinit, hbf, BH);

        for (int c0 = 0; c0 < T_STEPS; c0 += TC) {
            dim3 ggrid(G3 / 128, TC * BATCH / 128);
            gemm_gx_bf16<<<ggrid, 256, 0, stream>>>(
                A_all + (size_t)c0 * BH, wih_bf[layer], bih[layer],
                gx, TC * BATCH);

            const float* gxp = gx;
            const float* hprev0 = (c0 == 0) ? hinit : (y + (size_t)(c0 - 1) * BH);
            const unsigned short* whhp = whh_bf[layer];
            const float* bhhp = bhh[layer];
            float* yp = y;
            float* hnp = hn + (size_t)layer * BH;
            unsigned short* hbfp = hbf;
            unsigned int* flp = flags;
            int sb = layer * T_STEPS + c0;
            int t0v = c0, tcv = TC;
            void* kargs[] = {(void*)&gxp, (void*)&hbfp, (void*)&hprev0,
                             (void*)&whhp, (void*)&bhhp, (void*)&yp,
                             (void*)&hnp, (void*)&flp,
                             (void*)&sb, (void*)&t0v, (void*)&tcv};
            hipLaunchCooperativeKernel((const void*)gru_persist,
                                       dim3(256), dim3(256), kargs, 0, stream);
        }
    }
}

// Round 13
// 5686.808 us; speedup vs baseline: 1.4776x; 1.4776x over previous
//
#include <hip/hip_runtime.h>
#include <hip/hip_bf16.h>
#include <math.h>

#define T_STEPS 512
#define BATCH   64
#define HID     1024
#define G3      3072
#define BH      (BATCH * HID)

typedef __attribute__((ext_vector_type(8))) short          bf16x8;
typedef __attribute__((ext_vector_type(8))) unsigned short u16x8;
typedef __attribute__((ext_vector_type(4))) float          f32x4;
typedef unsigned long long u64;

__device__ inline unsigned short f2bf(float f) {
    __hip_bfloat16 h = __float2bfloat16(f);
    return *reinterpret_cast<unsigned short*>(&h);
}

// agent-scope (cross-XCD coherent) 16B load of bf16x8, bypassing stale L1/L2
__device__ inline bf16x8 load_h8(const unsigned short* p) {
    u64 lo = __hip_atomic_load((const u64*)p,       __ATOMIC_RELAXED, __HIP_MEMORY_SCOPE_AGENT);
    u64 hi = __hip_atomic_load((const u64*)(p + 4), __ATOMIC_RELAXED, __HIP_MEMORY_SCOPE_AGENT);
    union { u64 q[2]; bf16x8 v; } u;
    u.q[0] = lo; u.q[1] = hi;
    return u.v;
}

__device__ inline float fast_sigmoid(float x) {
    return __builtin_amdgcn_rcpf(1.f + __expf(-x));
}
__device__ inline float fast_tanh(float x) {
    float e = __expf(-2.f * fabsf(x));
    float t = (1.f - e) * __builtin_amdgcn_rcpf(1.f + e);
    return copysignf(t, x);
}

// ---------------------------------------------------------------------------
__global__ void cvt_f32_bf16(const float* __restrict__ src,
                             unsigned short* __restrict__ dst, int n)
{
    int i = (blockIdx.x * blockDim.x + threadIdx.x) * 4;
    if (i + 3 < n) {
        float4 v = *(const float4*)(src + i);
        ushort4 o;
        o.x = f2bf(v.x); o.y = f2bf(v.y); o.z = f2bf(v.z); o.w = f2bf(v.w);
        *(ushort4*)(dst + i) = o;
    }
}

// ---------------------------------------------------------------------------
// gx GEMM: C[M][3072] = A[M][1024](f32, cvt on the fly) @ Wbf[3072][1024]^T + b
// ---------------------------------------------------------------------------
__global__ __launch_bounds__(256) void gemm_gx_bf16(
    const float* __restrict__ A, const unsigned short* __restrict__ Wbf,
    const float* __restrict__ bias, float* __restrict__ C, int M)
{
    __shared__ unsigned short As[128][72];
    __shared__ unsigned short Bs[128][72];
    const int tid = threadIdx.x;
    const int l  = tid & 63;
    const int w  = tid >> 6;
    const int wm = w >> 1, wn = w & 1;
    const int m0 = blockIdx.y * 128, n0 = blockIdx.x * 128;
    const int lr = l & 15, lk = (l >> 4) * 8;

    f32x4 acc[4][4] = {};

    const int arow = tid >> 4, acol = (tid & 15) * 4;
    const int brow = tid >> 3, bcol = (tid & 7) * 8;

    for (int k0 = 0; k0 < 1024; k0 += 64) {
        float4 av[8];
        #pragma unroll
        for (int r = 0; r < 8; ++r)
            av[r] = *(const float4*)(A + (size_t)(m0 + r * 16 + arow) * 1024 + k0 + acol);
        u16x8 bv[4];
        #pragma unroll
        for (int r = 0; r < 4; ++r)
            bv[r] = *(const u16x8*)(Wbf + (size_t)(n0 + r * 32 + brow) * 1024 + k0 + bcol);

        __syncthreads();
        #pragma unroll
        for (int r = 0; r < 8; ++r) {
            ushort4 o;
            o.x = f2bf(av[r].x); o.y = f2bf(av[r].y);
            o.z = f2bf(av[r].z); o.w = f2bf(av[r].w);
            *(ushort4*)&As[r * 16 + arow][acol] = o;
        }
        #pragma unroll
        for (int r = 0; r < 4; ++r)
            *(u16x8*)&Bs[r * 32 + brow][bcol] = bv[r];
        __syncthreads();

        #pragma unroll
        for (int kk = 0; kk < 2; ++kk) {
            bf16x8 af[4], bfr[4];
            #pragma unroll
            for (int i = 0; i < 4; ++i)
                af[i] = *(const bf16x8*)&As[wm * 64 + i * 16 + lr][kk * 32 + lk];
            #pragma unroll
            for (int j = 0; j < 4; ++j)
                bfr[j] = *(const bf16x8*)&Bs[wn * 64 + j * 16 + lr][kk * 32 + lk];
            #pragma unroll
            for (int i = 0; i < 4; ++i)
                #pragma unroll
                for (int j = 0; j < 4; ++j)
                    acc[i][j] = __builtin_amdgcn_mfma_f32_16x16x32_bf16(
                        af[i], bfr[j], acc[i][j], 0, 0, 0);
        }
    }

    #pragma unroll
    for (int j = 0; j < 4; ++j) {
        const int col = n0 + wn * 64 + j * 16 + lr;
        const float bv = bias[col];
        #pragma unroll
        for (int i = 0; i < 4; ++i) {
            const int rb = m0 + wm * 64 + i * 16 + (l >> 4) * 4;
            #pragma unroll
            for (int r = 0; r < 4; ++r)
                C[(size_t)(rb + r) * G3 + col] = acc[i][j][r] + bv;
        }
    }
}

// ---------------------------------------------------------------------------
// Persistent recurrence (round-5 verified structure). RMW-free barrier:
// producer (jt,bg) stores a monotone stamp into its own flag word
// flags[bg*64+jt] (plain agent-scope store); consumer wave 0 polls all 64
// flags of its bg with one coalesced load + ballot. h-store->flag order
// guaranteed by the vmcnt(0) drain in the __syncthreads before the flag
// store. y-store, hn-store and gx-prefetch sit after the flag store (off the
// arrive path, hidden under the spin).
// ---------------------------------------------------------------------------
__global__ __launch_bounds__(256, 1) void gru_persist(
    const float* __restrict__ gx,            // [tc][64][3072] chunk-local
    unsigned short* __restrict__ hbf,        // 2 x [64][1024], parity = t&1
    const float* __restrict__ hprev0,        // [64][1024] f32 h before step t0
    const unsigned short* __restrict__ whh,  // [3072][1024] bf16
    const float* __restrict__ bhh,           // [3072]
    float* __restrict__ y_all,               // [512][64][1024]
    float* __restrict__ hn_dst,              // [64][1024] (this layer's hn)
    unsigned int* __restrict__ flags,        // [4][64] stamp words
    int step_base, int t0, int tc)
{
    __shared__ float red[4][64][13];

    const int tid = threadIdx.x;
    const int bid = blockIdx.x;
    const int jt = bid & 63;
    const int bg = bid >> 6;
    const int l   = tid & 63;
    const int ks  = tid >> 6;          // wave = k-slice (256 k)
    const int lr  = l & 15;
    const int lgrp = l >> 4;

    const unsigned short* hpb = hbf + (size_t)(bg * 16 + lr) * HID + ks * 256 + lgrp * 8;
    const unsigned short* wr  = whh + (size_t)(jt * 16 + lr) * HID + ks * 256 + lgrp * 8;
    const unsigned short* wz  = wr + (size_t)HID * HID;
    const unsigned short* wn  = wz + (size_t)HID * HID;

    // hoist this wave's W_hh slice into registers (loop-invariant)
    bf16x8 wvr[8], wvz[8], wvn[8];
    #pragma unroll
    for (int kc = 0; kc < 8; ++kc) {
        wvr[kc] = *(const bf16x8*)(wr + kc * 32);
        wvz[kc] = *(const bf16x8*)(wz + kc * 32);
        wvn[kc] = *(const bf16x8*)(wn + kc * 32);
    }

    // finalize coords: thread (fl, q) -> (col j, batch b)
    const int q  = tid >> 6;
    const int fl = tid & 63;
    const int j  = jt * 16 + (fl & 15);
    const int b  = bg * 16 + 4 * (fl >> 4) + q;
    const float brc = bhh[j], bzc = bhh[HID + j], bnc = bhh[2 * HID + j];
    float hreg = hprev0[(size_t)b * HID + j];

    float gxr = gx[(size_t)b * G3 + j];
    float gxz = gx[(size_t)b * G3 + HID + j];
    float gxn = gx[(size_t)b * G3 + 2 * HID + j];

    for (int ts = 0; ts < tc; ++ts) {
        const int t = t0 + ts;
        const size_t coff = (size_t)(t & 1) * BH;
        const size_t noff = (size_t)((t + 1) & 1) * BH;
        const unsigned int stamp = (unsigned int)(step_base + ts + 1);

        f32x4 ar = {0.f, 0.f, 0.f, 0.f};
        f32x4 az = {0.f, 0.f, 0.f, 0.f};
        f32x4 an = {0.f, 0.f, 0.f, 0.f};
        #pragma unroll
        for (int kc = 0; kc < 8; ++kc) {
            bf16x8 a = load_h8(hpb + coff + kc * 32);
            ar = __builtin_amdgcn_mfma_f32_16x16x32_bf16(a, wvr[kc], ar, 0, 0, 0);
            az = __builtin_amdgcn_mfma_f32_16x16x32_bf16(a, wvz[kc], az, 0, 0, 0);
            an = __builtin_amdgcn_mfma_f32_16x16x32_bf16(a, wvn[kc], an, 0, 0, 0);
        }
        #pragma unroll
        for (int i = 0; i < 4; ++i) {
            red[ks][l][i]     = ar[i];
            red[ks][l][4 + i] = az[i];
            red[ks][l][8 + i] = an[i];
        }
        __syncthreads();

        float sr = 0.f, sz = 0.f, sn = 0.f;
        #pragma unroll
        for (int s = 0; s < 4; ++s) {
            sr += red[s][fl][q];
            sz += red[s][fl][4 + q];
            sn += red[s][fl][8 + q];
        }
        const float rg = fast_sigmoid(gxr + sr + brc);
        const float zg = fast_sigmoid(gxz + sz + bzc);
        const float ng = fast_tanh(gxn + rg * (sn + bnc));
        hreg = ng + zg * (hreg - ng);

        // packed 4B agent-scope h store (lane pair shares one dword)
        unsigned int myu = (unsigned int)f2bf(hreg);
        unsigned int pu  = __shfl_xor(myu, 1);
        if (!(fl & 1))
            __hip_atomic_store((unsigned int*)(hbf + noff + (size_t)b * HID + j),
                               myu | (pu << 16),
                               __ATOMIC_RELAXED, __HIP_MEMORY_SCOPE_AGENT);

        __syncthreads();   // drains vmcnt(0): all h stores are at the LLC
        if (tid == 0)      // arrive: plain store, RMW-free
            __hip_atomic_store(&flags[bg * 64 + jt], stamp,
                               __ATOMIC_RELAXED, __HIP_MEMORY_SCOPE_AGENT);

        // off the arrive path: y store, hn store, next step's gx prefetch
        y_all[(size_t)t * BH + (size_t)b * HID + j] = hreg;
        if (t == T_STEPS - 1)
            hn_dst[(size_t)b * HID + j] = hreg;
        const int tsn = (ts + 1 < tc) ? ts + 1 : ts;
        const float* gxp = gx + (size_t)tsn * BATCH * G3;
        const float ngxr = gxp[(size_t)b * G3 + j];
        const float ngxz = gxp[(size_t)b * G3 + HID + j];
        const float ngxn = gxp[(size_t)b * G3 + 2 * HID + j];

        if (tid < 64) {    // wave 0 polls all 64 producer flags of this bg
            for (;;) {
                unsigned int f = __hip_atomic_load(&flags[bg * 64 + tid],
                                                   __ATOMIC_RELAXED,
                                                   __HIP_MEMORY_SCOPE_AGENT);
                if (__ballot(f >= stamp) == ~0ull) break;
                __builtin_amdgcn_s_sleep(1);
            }
        }
        __syncthreads();   // release: all 64 bg-blocks' h visible; guards red
        gxr = ngxr; gxz = ngxz; gxn = ngxn;
    }
}

// ---------------------------------------------------------------------------
extern "C" void kernel_launch(void* const* d_in, const int* in_sizes, int n_in,
                              void* d_out, int out_size, void* d_ws, size_t ws_size,
                              hipStream_t stream)
{
    const float* x    = (const float*)d_in[0];
    const float* h0   = (const float*)d_in[1];
    const float* wih[2] = {(const float*)d_in[2], (const float*)d_in[6]};
    const float* whh[2] = {(const float*)d_in[3], (const float*)d_in[7]};
    const float* bih[2] = {(const float*)d_in[4], (const float*)d_in[8]};
    const float* bhh[2] = {(const float*)d_in[5], (const float*)d_in[9]};

    float* out = (float*)d_out;
    float* y   = out;                                  // [512][64][1024]
    float* hn  = out + (size_t)T_STEPS * BH;           // [2][64][1024]

    const size_t WSZ = (size_t)G3 * HID;               // 3145728 elems
    unsigned short* wsu = (unsigned short*)d_ws;
    unsigned short* whh_bf[2] = {wsu, wsu + WSZ};
    unsigned short* wih_bf[2] = {wsu + 2 * WSZ, wsu + 3 * WSZ};
    unsigned short* hbf = wsu + 4 * WSZ;               // 2 x BH bf16 ping-pong
    unsigned int* flags = (unsigned int*)(wsu + 4 * WSZ + 2 * (size_t)BH);
    const size_t FLAG_N = 4 * 64;
    float* gx = (float*)((char*)flags + FLAG_N * sizeof(unsigned int));
    const size_t fixed_bytes = (4 * WSZ + 2 * (size_t)BH) * 2 + FLAG_N * 4;
    const size_t gx_bytes = ws_size > fixed_bytes ? ws_size - fixed_bytes : 0;

    int TC = 512;
    while (TC > 2 && (size_t)TC * BATCH * G3 * 4 > gx_bytes) TC >>= 1;

    hipMemsetAsync(flags, 0, FLAG_N * sizeof(unsigned int), stream);

    for (int layer = 0; layer < 2; ++layer) {
        cvt_f32_bf16<<<(int)(WSZ / 1024), 256, 0, stream>>>(whh[layer], whh_bf[layer], (int)WSZ);
        cvt_f32_bf16<<<(int)(WSZ / 1024), 256, 0, stream>>>(wih[layer], wih_bf[layer], (int)WSZ);
    }

    for (int layer = 0; layer < 2; ++layer) {
        const float* A_all = (layer == 0) ? x : y;
        const float* hinit = h0 + (size_t)layer * BH;

        cvt_f32_bf16<<<BH / 1024, 256, 0, stream>>>(hinit, hbf, BH);

        for (int c0 = 0; c0 < T_STEPS; c0 += TC) {
            dim3 ggrid(G3 / 128, TC * BATCH / 128);
            gemm_gx_bf16<<<ggrid, 256, 0, stream>>>(
                A_all + (size_t)c0 * BH, wih_bf[layer], bih[layer],
                gx, TC * BATCH);

            const float* gxp = gx;
            const float* hprev0 = (c0 == 0) ? hinit : (y + (size_t)(c0 - 1) * BH);
            const unsigned short* whhp = whh_bf[layer];
            const float* bhhp = bhh[layer];
            float* yp = y;
            float* hnp = hn + (size_t)layer * BH;
            unsigned short* hbfp = hbf;
            unsigned int* flp = flags;
            int sb = layer * T_STEPS + c0;
            int t0v = c0, tcv = TC;
            void* kargs[] = {(void*)&gxp, (void*)&hbfp, (void*)&hprev0,
                             (void*)&whhp, (void*)&bhhp, (void*)&yp,
                             (void*)&hnp, (void*)&flp,
                             (void*)&sb, (void*)&t0v, (void*)&tcv};
            hipLaunchCooperativeKernel((const void*)gru_persist,
                                       dim3(256), dim3(256), kargs, 0, stream);
        }
    }
}